// Round 14
// baseline (1915.405 us; speedup 1.0000x reference)
//
#include <hip/hip_runtime.h>
#include <stdint.h>

// ---------------------------------------------------------------------------
// BondMatrixMessage: messages[b,e,i] = sum_{k,j} bond[b,e,k] W[k,i,j] src[b,e,j]
// GEMM recast: C[16384 x 64] = A[16384 x 4096] @ W2[4096 x 64]
// R14: INSTRUMENTATION. Kernel = R13 (col-split, 8-phase producer-consumer,
// counted vmcnt) + DREPS=16 rep loop (opq re-zero, unroll 1) launched x3.
// All 3 dispatches land 50-160us -> top-5 shows per-dispatch dur (-> hot
// loop time/rep), Start/End timestamps (-> inter-launch GAP, the number
// never yet measured), and MfmaUtil/VALUBusy/FETCH for the production
// structure. Decomposes R9's 13.6us = kernel + gap.
// conn is int32 (harness narrows int64): src idx = conn[e*2].
// ---------------------------------------------------------------------------

#define NATOMS 256
#define DIM 64
#define BT 128   // bonds per block
#define DREPS 16 // diagnostic reps; 1 for production

typedef _Float16 f16;
typedef _Float16 f16x2 __attribute__((ext_vector_type(2)));
typedef _Float16 f16x8 __attribute__((ext_vector_type(8)));
typedef float f32x16 __attribute__((ext_vector_type(16)));

#define AS1 __attribute__((address_space(1)))
#define AS3 __attribute__((address_space(3)))

union H8 { f16x8 v8; f16x2 v2[4]; };

static __device__ __forceinline__ void gll16(const void* g, void* l) {
    __builtin_amdgcn_global_load_lds((AS1 void*)(uintptr_t)g, (AS3 void*)l, 16, 0, 0);
}

static __device__ __forceinline__ void wave_barrier() {
    __builtin_amdgcn_sched_barrier(0);
    __builtin_amdgcn_s_barrier();
    __builtin_amdgcn_sched_barrier(0);
}

// prep: cast + permute bt (64 x 4096 f32) into col-split fragment order.
__global__ __launch_bounds__(256) void prep_w2f(const float* __restrict__ bt,
                                                f16* __restrict__ w2f) {
    const int d  = blockIdx.x * 256 + threadIdx.x;   // 32768 chunks
    const int k  = d >> 9, c = d & 511;
    const int ch = c >> 8, s = (c >> 6) & 3, l = c & 63;
    const int col = ch * 32 + (l & 31);
    const float* src = bt + (size_t)k * 4096 + col * 64 + s * 16 + (l >> 5) * 8;
    const float4 p = *reinterpret_cast<const float4*>(src);
    const float4 q = *reinterpret_cast<const float4*>(src + 4);
    const f16x8 h = { (f16)p.x, (f16)p.y, (f16)p.z, (f16)p.w,
                      (f16)q.x, (f16)q.y, (f16)q.z, (f16)q.w };
    reinterpret_cast<f16x8*>(w2f)[d] = h;
}

static __device__ __forceinline__ unsigned swz16(unsigned lane) {
    return (lane * 16u) ^ ((lane & 0x38u) << 1);
}

__global__ __launch_bounds__(512, 1) void bond_msg(
    const float* __restrict__ atom, const float* __restrict__ bond,
    const int* __restrict__ conn, const f16* __restrict__ w2f,
    float* __restrict__ out)
{
    // LDS: stage ring buf[pb(2)][kh(2)][q(4)][s(4)][64 x 16B] = 64 KB.
    //      epilogue reuses [0,16K) for kh-pair reduce.
    __shared__ __align__(16) unsigned char smem[65536];

    const int tid  = threadIdx.x;
    const int lane = tid & 63;
    const int w    = tid >> 6;     // wave 0..7
    const int mt   = w & 3;        // m-tile (32 bonds each)
    const int kh   = w >> 2;       // k half
    const int lo   = lane & 31;
    const int hi   = lane >> 5;
    const int blk  = blockIdx.x;
    const int btile = blk >> 1;    // bond tile 0..127
    const int ch   = blk & 1;      // column half (32 cols)
    const int bond0 = btile * BT;

    const char* gw = reinterpret_cast<const char*>(w2f)
                   + (size_t)ch * 4096 + (size_t)lane * 16;
    char* lst = reinterpret_cast<char*>(smem) + kh * 16384 + mt * 4096;
    const char* lrd = reinterpret_cast<const char*>(smem) + kh * 16384 + lane * 16;

    #define ISSUE(p) do {                                                 \
        const char* _g = gw + (size_t)(kh * 32 + (p) * 4 + mt) * 8192;    \
        char* _l = lst + ((p) & 1) * 32768;                               \
        gll16(_g,        _l);                                             \
        gll16(_g + 1024, _l + 1024);                                      \
        gll16(_g + 2048, _l + 2048);                                      \
        gll16(_g + 3072, _l + 3072);                                      \
    } while (0)

    // ---- this wave's bond row e and its 32 k-values (dup'd f16 pairs)
    const int e = bond0 + mt * 32 + lo;
    const int ia = conn[e * 2];
    f16x2 bp[32];
    {
        const float* brow = bond + (size_t)e * DIM + kh * 32;
        #pragma unroll
        for (int q = 0; q < 8; ++q) {
            const float4 v = *reinterpret_cast<const float4*>(brow + q * 4);
            const f16 a0 = (f16)v.x, a1 = (f16)v.y, a2 = (f16)v.z, a3 = (f16)v.w;
            bp[q*4+0] = (f16x2){a0,a0}; bp[q*4+1] = (f16x2){a1,a1};
            bp[q*4+2] = (f16x2){a2,a2}; bp[q*4+3] = (f16x2){a3,a3};
        }
    }

    // ---- src atom row -> registers (f16 pairs); j = s*16 + hi*8 + {0..7}
    const float* arow = atom + (size_t)(btile >> 2) * (NATOMS * DIM)
                      + (size_t)ia * DIM;
    f16x2 srcv[4][4];
    #pragma unroll
    for (int s = 0; s < 4; ++s) {
        const int j0 = s * 16 + hi * 8;
        const float4 p0 = *reinterpret_cast<const float4*>(arow + j0);
        const float4 p1 = *reinterpret_cast<const float4*>(arow + j0 + 4);
        srcv[s][0] = (f16x2){ (f16)p0.x, (f16)p0.y };
        srcv[s][1] = (f16x2){ (f16)p0.z, (f16)p0.w };
        srcv[s][2] = (f16x2){ (f16)p1.x, (f16)p1.y };
        srcv[s][3] = (f16x2){ (f16)p1.z, (f16)p1.w };
    }

    // ---- main loop: DREPS x (8 phases x 4 kg x 4 s); opq re-zero per rep
    f32x16 acc = {};
    const bool opq = (ia > -2000000000);   // runtime-true; defeats rep DCE/LICM

    #define STEP(p, wtxt) do {                                            \
        if ((p) + 1 < 8) ISSUE((p) + 1);                                  \
        asm volatile("s_waitcnt vmcnt(" wtxt ")" ::: "memory");           \
        wave_barrier();                                                   \
        {                                                                 \
            const char* _rb = lrd + ((p) & 1) * 32768;                    \
            _Pragma("unroll")                                             \
            for (int q = 0; q < 4; ++q) {                                 \
                const f16x2 _c = bp[(p) * 4 + q];                         \
                _Pragma("unroll")                                         \
                for (int s = 0; s < 4; ++s) {                             \
                    const f16x8 bf = *reinterpret_cast<const f16x8*>(     \
                        _rb + q * 4096 + s * 1024);                       \
                    H8 _a;                                                \
                    _Pragma("unroll")                                     \
                    for (int t = 0; t < 4; ++t) _a.v2[t] = _c * srcv[s][t]; \
                    acc = __builtin_amdgcn_mfma_f32_32x32x16_f16(_a.v8, bf, acc, 0, 0, 0); \
                }                                                         \
            }                                                             \
        }                                                                 \
        wave_barrier();                                                   \
    } while (0)

    #pragma unroll 1
    for (int rep = 0; rep < DREPS; ++rep) {
        if (opq) acc = (f32x16){};
        ISSUE(0);
        STEP(0, "4"); STEP(1, "4"); STEP(2, "4"); STEP(3, "4");
        STEP(4, "4"); STEP(5, "4"); STEP(6, "4"); STEP(7, "0");
    }

    #undef STEP
    #undef ISSUE

    // ---- epilogue: kh-pair reduce through LDS [0,16K), kh=0 writes C
    __syncthreads();
    if (kh == 1) {
        const unsigned so = swz16((unsigned)lane);
        #pragma unroll
        for (int g = 0; g < 4; ++g) {
            float4 v = { acc[4*g+0], acc[4*g+1], acc[4*g+2], acc[4*g+3] };
            *reinterpret_cast<float4*>(smem + mt*4096 + g*1024 + so) = v;
        }
    }
    __syncthreads();
    if (kh == 0) {
        const unsigned so = swz16((unsigned)lane);
        #pragma unroll
        for (int g = 0; g < 4; ++g) {
            const float4 v = *reinterpret_cast<const float4*>(
                smem + mt*4096 + g*1024 + so);
            acc[4*g+0] += v.x; acc[4*g+1] += v.y;
            acc[4*g+2] += v.z; acc[4*g+3] += v.w;
        }
        const int colb = ch * 32 + lo;
        #pragma unroll
        for (int r = 0; r < 16; ++r) {
            // C/D map: col = lane&31, row = (r&3) + 8*(r>>2) + 4*(lane>>5)
            const int rl = (r & 3) + 8 * (r >> 2) + 4 * hi;
            out[(size_t)(bond0 + mt * 32 + rl) * 64 + colb] = acc[r];
        }
    }
}

// ---- fallback (ws too small): f32, LDS-staged, correct.
__global__ __launch_bounds__(256) void bond_fallback(
    const float* __restrict__ atom, const float* __restrict__ bond,
    const int* __restrict__ conn, const float* __restrict__ bt,
    float* __restrict__ out)
{
    __shared__ float Wk[4096];
    __shared__ float srcs[4][64];
    __shared__ float bnds[4][64];
    const int blk = blockIdx.x;
    const int e0 = blk * 4;
    const int b = e0 >> 9;
    const int t = threadIdx.x;
    const int il = t & 63, eg = t >> 6;
    const int e = e0 + eg;
    const int ia = conn[e * 2];
    srcs[eg][il] = atom[(size_t)b * (NATOMS * DIM) + (size_t)ia * DIM + il];
    bnds[eg][il] = bond[(size_t)e * DIM + il];
    float acc = 0.f;
    for (int k = 0; k < 64; ++k) {
        __syncthreads();
        #pragma unroll
        for (int c = 0; c < 4; ++c) {
            float4 v = reinterpret_cast<const float4*>(bt + (size_t)k * 4096)[t + c * 256];
            reinterpret_cast<float4*>(Wk)[t + c * 256] = v;
        }
        __syncthreads();
        float s = 0.f;
        #pragma unroll
        for (int j = 0; j < 64; ++j) s += Wk[il * 64 + j] * srcs[eg][j];
        acc += bnds[eg][k] * s;
    }
    out[(size_t)e * DIM + il] = acc;
}

extern "C" void kernel_launch(void* const* d_in, const int* in_sizes, int n_in,
                              void* d_out, int out_size, void* d_ws, size_t ws_size,
                              hipStream_t stream) {
    const float* atom = (const float*)d_in[0];   // (32,256,64) f32
    const float* bond = (const float*)d_in[1];   // (32,512,64) f32
    const int*   conn = (const int*)d_in[2];     // (32,512,2) int32 (narrowed)
    const float* bt   = (const float*)d_in[3];   // (64,4096) f32
    float* out = (float*)d_out;                  // (32,512,64) f32

    if (ws_size >= (size_t)64 * 4096 * sizeof(f16)) {
        f16* w2f = (f16*)d_ws;                   // 512 KB scratch
        prep_w2f<<<128, 256, 0, stream>>>(bt, w2f);
        // R14: three instrumented launches (idempotent). Timestamps of the
        // three dispatches in the top-5 give the inter-launch gap directly.
        bond_msg<<<256, 512, 0, stream>>>(atom, bond, conn, w2f, out);
        bond_msg<<<256, 512, 0, stream>>>(atom, bond, conn, w2f, out);
        bond_msg<<<256, 512, 0, stream>>>(atom, bond, conn, w2f, out);
    } else {
        bond_fallback<<<4096, 256, 0, stream>>>(atom, bond, conn, bt, out);
    }
}

// Round 15
// 21.996 us; speedup vs baseline: 87.0781x; 87.0781x over previous
//
#include <hip/hip_runtime.h>
#include <stdint.h>

// ---------------------------------------------------------------------------
// BondMatrixMessage: messages[b,e,i] = sum_{k,j} bond[b,e,k] W[k,i,j] src[b,e,j]
// GEMM recast: C[16384 x 64] = A[16384 x 4096] @ W2[4096 x 64]
//   A[e, k*64+j] = bond[e,k]*src[e,j]  (registers, v_pk_mul_f16)
//   W2 prep-cast to f16 in MFMA-fragment order (w2f) by prep kernel.
// R15: staging mechanism fix. R14 instrumentation: global_load_lds traffic
// is NOT served by L2 (1.45 GB fetched re-reading a 512 KB table 16x;
// R4's plain-load version of the same read: 6 MB). Every gll-based round
// paid full memory traffic per pass -> the invariant ~13 us. Fix = T14:
// stage via plain global_load_dwordx4 -> regs (issued EARLY, L2-cacheable),
// compute, then ds_write_b128 LATE (vmcnt wait auto-inserted by compiler),
// double reg-sets (sA/sB) to break WAR, sched_barrier(0) pins order,
// lgkmcnt(0)+s_barrier per phase for cross-wave visibility.
// Structure otherwise = R13: 256 blocks = 128 bond-tiles x 2 col-halves
// (64 MB aggregate L2-read, ~4 MB HBM first-touch); 8 waves = 4 m-tiles x
// 2 k-halves sharing staged streams; 8 phases; kh-pair reduce epilogue.
// conn is int32 (harness narrows int64): src idx = conn[e*2].
// ---------------------------------------------------------------------------

#define NATOMS 256
#define DIM 64
#define BT 128   // bonds per block

typedef _Float16 f16;
typedef _Float16 f16x2 __attribute__((ext_vector_type(2)));
typedef _Float16 f16x8 __attribute__((ext_vector_type(8)));
typedef float f32x16 __attribute__((ext_vector_type(16)));

union H8 { f16x8 v8; f16x2 v2[4]; };

// prep: cast + permute bt (64 x 4096 f32) into col-split fragment order.
// Chunk d = k*512 + ch*256 + s*64 + l (16B each):
//   col = ch*32 + (l&31);  elems = bt[k][col*64 + s*16 + (l>>5)*8 + 0..8)
__global__ __launch_bounds__(256) void prep_w2f(const float* __restrict__ bt,
                                                f16* __restrict__ w2f) {
    const int d  = blockIdx.x * 256 + threadIdx.x;   // 32768 chunks
    const int k  = d >> 9, c = d & 511;
    const int ch = c >> 8, s = (c >> 6) & 3, l = c & 63;
    const int col = ch * 32 + (l & 31);
    const float* src = bt + (size_t)k * 4096 + col * 64 + s * 16 + (l >> 5) * 8;
    const float4 p = *reinterpret_cast<const float4*>(src);
    const float4 q = *reinterpret_cast<const float4*>(src + 4);
    const f16x8 h = { (f16)p.x, (f16)p.y, (f16)p.z, (f16)p.w,
                      (f16)q.x, (f16)q.y, (f16)q.z, (f16)q.w };
    reinterpret_cast<f16x8*>(w2f)[d] = h;
}

static __device__ __forceinline__ unsigned swz16(unsigned lane) {
    return (lane * 16u) ^ ((lane & 0x38u) << 1);
}

__global__ __launch_bounds__(512, 1) void bond_msg(
    const float* __restrict__ atom, const float* __restrict__ bond,
    const int* __restrict__ conn, const f16* __restrict__ w2f,
    float* __restrict__ out)
{
    // LDS: stage ring buf[pb(2)][kh(2)][q(4)][s(4)][64 x 16B] = 64 KB.
    //      epilogue reuses [0,16K) for kh-pair reduce.
    __shared__ __align__(16) unsigned char smem[65536];

    const int tid  = threadIdx.x;
    const int lane = tid & 63;
    const int w    = tid >> 6;     // wave 0..7
    const int mt   = w & 3;        // m-tile (32 bonds each)
    const int kh   = w >> 2;       // k half (k in [kh*32, kh*32+32))
    const int lo   = lane & 31;
    const int hi   = lane >> 5;
    const int blk  = blockIdx.x;
    const int btile = blk >> 1;    // bond tile 0..127
    const int ch   = blk & 1;      // column half (32 cols)
    const int bond0 = btile * BT;  // 4 tiles per batch; never straddles

    // w2f bytes: k*8192 + ch*4096 + s*1024 + lane*16
    const char* gw = reinterpret_cast<const char*>(w2f)
                   + (size_t)ch * 4096 + (size_t)lane * 16;
    char* lstw = reinterpret_cast<char*>(smem) + kh * 16384 + mt * 4096
               + lane * 16;                      // this wave's write slot
    const char* lrd = reinterpret_cast<const char*>(smem) + kh * 16384 + lane * 16;

    // ---- this wave's bond row e and its 32 k-values (dup'd f16 pairs)
    const int e = bond0 + mt * 32 + lo;
    const int ia = conn[e * 2];
    f16x2 bp[32];
    {
        const float* brow = bond + (size_t)e * DIM + kh * 32;
        #pragma unroll
        for (int q = 0; q < 8; ++q) {
            const float4 v = *reinterpret_cast<const float4*>(brow + q * 4);
            const f16 a0 = (f16)v.x, a1 = (f16)v.y, a2 = (f16)v.z, a3 = (f16)v.w;
            bp[q*4+0] = (f16x2){a0,a0}; bp[q*4+1] = (f16x2){a1,a1};
            bp[q*4+2] = (f16x2){a2,a2}; bp[q*4+3] = (f16x2){a3,a3};
        }
    }

    // ---- src atom row -> registers (f16 pairs); j = s*16 + hi*8 + {0..7}
    const float* arow = atom + (size_t)(btile >> 2) * (NATOMS * DIM)
                      + (size_t)ia * DIM;
    f16x2 srcv[4][4];
    #pragma unroll
    for (int s = 0; s < 4; ++s) {
        const int j0 = s * 16 + hi * 8;
        const float4 p0 = *reinterpret_cast<const float4*>(arow + j0);
        const float4 p1 = *reinterpret_cast<const float4*>(arow + j0 + 4);
        srcv[s][0] = (f16x2){ (f16)p0.x, (f16)p0.y };
        srcv[s][1] = (f16x2){ (f16)p0.z, (f16)p0.w };
        srcv[s][2] = (f16x2){ (f16)p1.x, (f16)p1.y };
        srcv[s][3] = (f16x2){ (f16)p1.z, (f16)p1.w };
    }

    // ---- T14 staging: plain loads -> regs (early) ... ds_write (late).
    // Wave (mt,kh) owns kg = kh*32 + p*4 + mt for phase p in [0,8).
    f16x8 sA[4], sB[4];

    #define LOADR(S, p) do { if ((p) < 8) {                               \
        const char* _g = gw + (size_t)(kh * 32 + (p) * 4 + mt) * 8192;    \
        S[0] = *reinterpret_cast<const f16x8*>(_g);                       \
        S[1] = *reinterpret_cast<const f16x8*>(_g + 1024);                \
        S[2] = *reinterpret_cast<const f16x8*>(_g + 2048);                \
        S[3] = *reinterpret_cast<const f16x8*>(_g + 3072);                \
    } } while (0)

    #define WRITE(S, p) do { if ((p) < 8) {                               \
        char* _l = lstw + ((p) & 1) * 32768;                              \
        *reinterpret_cast<f16x8*>(_l)        = S[0];                      \
        *reinterpret_cast<f16x8*>(_l + 1024) = S[1];                      \
        *reinterpret_cast<f16x8*>(_l + 2048) = S[2];                      \
        *reinterpret_cast<f16x8*>(_l + 3072) = S[3];                      \
    } } while (0)

    #define LDSBAR() do {                                                 \
        asm volatile("s_waitcnt lgkmcnt(0)" ::: "memory");                \
        __builtin_amdgcn_s_barrier();                                     \
        __builtin_amdgcn_sched_barrier(0);                                \
    } while (0)

    f32x16 acc = {};

    #define COMPUTE(p) do {                                               \
        const char* _rb = lrd + ((p) & 1) * 32768;                        \
        _Pragma("unroll")                                                 \
        for (int q = 0; q < 4; ++q) {                                     \
            const f16x2 _c = bp[(p) * 4 + q];                             \
            _Pragma("unroll")                                             \
            for (int s = 0; s < 4; ++s) {                                 \
                const f16x8 bf = *reinterpret_cast<const f16x8*>(         \
                    _rb + q * 4096 + s * 1024);                           \
                H8 _a;                                                    \
                _Pragma("unroll")                                         \
                for (int t = 0; t < 4; ++t) _a.v2[t] = _c * srcv[s][t];   \
                acc = __builtin_amdgcn_mfma_f32_32x32x16_f16(_a.v8, bf, acc, 0, 0, 0); \
            }                                                             \
        }                                                                 \
    } while (0)

    // STEP(p,S): issue loads for p+1 (early), compute p, write p+1 (late).
    #define STEP(p, S) do {                                               \
        LOADR(S, (p) + 1);                                                \
        __builtin_amdgcn_sched_barrier(0);                                \
        COMPUTE(p);                                                       \
        __builtin_amdgcn_sched_barrier(0);                                \
        WRITE(S, (p) + 1);  /* compiler inserts vmcnt wait before write */ \
        LDSBAR();                                                         \
    } while (0)

    // prologue: phase 0 staged via sA
    LOADR(sA, 0);
    WRITE(sA, 0);
    LDSBAR();

    STEP(0, sB); STEP(1, sA); STEP(2, sB); STEP(3, sA);
    STEP(4, sB); STEP(5, sA); STEP(6, sB);
    COMPUTE(7);

    #undef STEP
    #undef COMPUTE
    #undef LDSBAR
    #undef WRITE
    #undef LOADR

    // ---- epilogue: kh-pair reduce through LDS [0,16K), kh=0 writes C
    __syncthreads();
    if (kh == 1) {
        const unsigned so = swz16((unsigned)lane);
        #pragma unroll
        for (int g = 0; g < 4; ++g) {
            float4 v = { acc[4*g+0], acc[4*g+1], acc[4*g+2], acc[4*g+3] };
            *reinterpret_cast<float4*>(smem + mt*4096 + g*1024 + so) = v;
        }
    }
    __syncthreads();
    if (kh == 0) {
        const unsigned so = swz16((unsigned)lane);
        #pragma unroll
        for (int g = 0; g < 4; ++g) {
            const float4 v = *reinterpret_cast<const float4*>(
                smem + mt*4096 + g*1024 + so);
            acc[4*g+0] += v.x; acc[4*g+1] += v.y;
            acc[4*g+2] += v.z; acc[4*g+3] += v.w;
        }
        const int colb = ch * 32 + lo;
        #pragma unroll
        for (int r = 0; r < 16; ++r) {
            // C/D map: col = lane&31, row = (r&3) + 8*(r>>2) + 4*(lane>>5)
            const int rl = (r & 3) + 8 * (r >> 2) + 4 * hi;
            out[(size_t)(bond0 + mt * 32 + rl) * 64 + colb] = acc[r];
        }
    }
}

// ---- fallback (ws too small): f32, LDS-staged, correct.
__global__ __launch_bounds__(256) void bond_fallback(
    const float* __restrict__ atom, const float* __restrict__ bond,
    const int* __restrict__ conn, const float* __restrict__ bt,
    float* __restrict__ out)
{
    __shared__ float Wk[4096];
    __shared__ float srcs[4][64];
    __shared__ float bnds[4][64];
    const int blk = blockIdx.x;
    const int e0 = blk * 4;
    const int b = e0 >> 9;
    const int t = threadIdx.x;
    const int il = t & 63, eg = t >> 6;
    const int e = e0 + eg;
    const int ia = conn[e * 2];
    srcs[eg][il] = atom[(size_t)b * (NATOMS * DIM) + (size_t)ia * DIM + il];
    bnds[eg][il] = bond[(size_t)e * DIM + il];
    float acc = 0.f;
    for (int k = 0; k < 64; ++k) {
        __syncthreads();
        #pragma unroll
        for (int c = 0; c < 4; ++c) {
            float4 v = reinterpret_cast<const float4*>(bt + (size_t)k * 4096)[t + c * 256];
            reinterpret_cast<float4*>(Wk)[t + c * 256] = v;
        }
        __syncthreads();
        float s = 0.f;
        #pragma unroll
        for (int j = 0; j < 64; ++j) s += Wk[il * 64 + j] * srcs[eg][j];
        acc += bnds[eg][k] * s;
    }
    out[(size_t)e * DIM + il] = acc;
}

extern "C" void kernel_launch(void* const* d_in, const int* in_sizes, int n_in,
                              void* d_out, int out_size, void* d_ws, size_t ws_size,
                              hipStream_t stream) {
    const float* atom = (const float*)d_in[0];   // (32,256,64) f32
    const float* bond = (const float*)d_in[1];   // (32,512,64) f32
    const int*   conn = (const int*)d_in[2];     // (32,512,2) int32 (narrowed)
    const float* bt   = (const float*)d_in[3];   // (64,4096) f32
    float* out = (float*)d_out;                  // (32,512,64) f32

    if (ws_size >= (size_t)64 * 4096 * sizeof(f16)) {
        f16* w2f = (f16*)d_ws;                   // 512 KB scratch
        prep_w2f<<<128, 256, 0, stream>>>(bt, w2f);
        bond_msg<<<256, 512, 0, stream>>>(atom, bond, conn, w2f, out);
    } else {
        bond_fallback<<<4096, 256, 0, stream>>>(atom, bond, conn, bt, out);
    }
}